// Round 3
// baseline (110.501 us; speedup 1.0000x reference)
//
#include <hip/hip_runtime.h>
#include <stdint.h>

// SpottingLoss: B=2048, N=64, F=19. Two-phase greedy auction matching
// (bitwise-exact replica of the reference lax.scan; validated absmax 0.0
// in R1/R2) + permuted loss -> scalar.
//
// One block == one wave == one batch; lane i == row i; lane i also owns
// column i for kill detection. Latency-bound (2 waves/SIMD, grid-limited).
//
// R3 changes (theory: R2's VGPR_Count=52 proves D1 row was NOT register-
// resident; rescan paid serial reload chain every round):
//  - __launch_bounds__(64,2): VGPR cap 256 (occupancy is grid-limited, regs
//    are free). D1 row held in 64 VGPRs.
//  - rescan = log-depth trees: masked fmaxf tree (-> v_max3_f32) for the
//    value, then min-index tree over fp-equality for JAX first-index ties.
//    Exact: D1 in (0,1], masked entries +0.0, equality on f32 bits.
//  - round logic: a bid always kills its column (any bid => column matched
//    to best bidder), so loser <=> rescan; winner <=> key_sh[jmax]==mykey
//    (keys unique per row). Both LDS reads issue before one wait.

#define NN 64
#define NF 19
#define ROWF (NN * NF)   // 1216
#define ROW4 (ROWF / 4)  // 304

__device__ __forceinline__ unsigned umin2(unsigned a, unsigned b) {
  return a < b ? a : b;
}

__global__ __launch_bounds__(64, 2) void spotting_loss_kernel(
    const float* __restrict__ yt, const float* __restrict__ yp,
    float* __restrict__ out)
{
  const int b = blockIdx.x;
  const int i = threadIdx.x;

  __shared__ float yp_sh[ROWF];
  __shared__ unsigned long long key_sh[NN];

  const float* __restrict__ ytb = yt + (size_t)b * ROWF;
  const float4* __restrict__ yp4 = (const float4*)(yp + (size_t)b * ROWF);
  float4* yp_sh4 = (float4*)yp_sh;
#pragma unroll
  for (int t = 0; t < 5; ++t) {
    const int idx = t * NN + i;
    if (idx < ROW4) yp_sh4[idx] = yp4[idx];
  }
  key_sh[i] = 0ull;               // tag 0 == never written
  const float alpha = ytb[i * NF + 0];
  const float x     = ytb[i * NF + 1];
  __syncthreads();

  // D1 row in registers (broadcast LDS reads: same address across lanes).
  float D1v[NN];
#pragma unroll
  for (int j = 0; j < NN; ++j)
    D1v[j] = 1.0f - fabsf(x - yp_sh[j * NF + 1]);

  unsigned long long hbits = ~0ull;  // active columns
  int perm = 0, jmax = 0;
  unsigned long long mykey = 0;
  float best = 0.0f;
  unsigned tag = 0;

  for (int phase = 0; phase < 2; ++phase) {
    bool vlive  = (phase == 0) ? (alpha > 0.5f) : (alpha < 0.5f);
    bool rescan = vlive;

    for (int it = 0; it < NN; ++it) {
      if (__ballot(vlive) == 0ull) break;
      ++tag;

      if (rescan) {
        // masked values (inactive -> +0.0; live lanes always have an
        // active column with D1 > 0, so best > 0)
        float m[NN];
#pragma unroll
        for (int j = 0; j < NN; ++j)
          m[j] = ((hbits >> j) & 1ull) ? D1v[j] : 0.0f;

        // value max, log depth
        float t32[32], t16[16], t8[8], t4[4];
#pragma unroll
        for (int j = 0; j < 32; ++j) t32[j] = fmaxf(m[j], m[j + 32]);
#pragma unroll
        for (int j = 0; j < 16; ++j) t16[j] = fmaxf(t32[j], t32[j + 16]);
#pragma unroll
        for (int j = 0; j < 8; ++j)  t8[j]  = fmaxf(t16[j], t16[j + 8]);
#pragma unroll
        for (int j = 0; j < 4; ++j)  t4[j]  = fmaxf(t8[j], t8[j + 4]);
        best = fmaxf(fmaxf(t4[0], t4[1]), fmaxf(t4[2], t4[3]));

        // first index achieving best (JAX first-index tie-break)
        unsigned c32[32], c16[16], c8[8], c4[4];
#pragma unroll
        for (int j = 0; j < 32; ++j) {
          const unsigned a0 = (m[j]      == best) ? (unsigned)j        : 255u;
          const unsigned a1 = (m[j + 32] == best) ? (unsigned)(j + 32) : 255u;
          c32[j] = umin2(a0, a1);
        }
#pragma unroll
        for (int j = 0; j < 16; ++j) c16[j] = umin2(c32[j], c32[j + 16]);
#pragma unroll
        for (int j = 0; j < 8; ++j)  c8[j]  = umin2(c16[j], c16[j + 8]);
#pragma unroll
        for (int j = 0; j < 4; ++j)  c4[j]  = umin2(c8[j], c8[j + 4]);
        jmax = (int)umin2(umin2(c4[0], c4[1]), umin2(c4[2], c4[3]));
        rescan = false;
      }

      if (vlive) {
        mykey = ((unsigned long long)tag << 38) |
                ((unsigned long long)__float_as_uint(best) << 6) |
                (unsigned long long)(63 - i);
        atomicMax(&key_sh[jmax], mykey);
      }
      __builtin_amdgcn_wave_barrier();  // DS pipe is in-order within a wave

      const unsigned long long kc = key_sh[i];     // my column's key
      const unsigned long long kw = key_sh[jmax];  // my target's key
      const unsigned long long killed =
          __ballot((unsigned)(kc >> 38) == tag);   // fresh tag == matched col

      if (vlive) {
        if (kw == mykey) {        // I am the best bidder -> matched
          perm = jmax;
          vlive = false;
        } else {
          rescan = true;          // my column was taken by a stronger bidder
        }
      }
      hbits &= ~killed;
      __builtin_amdgcn_wave_barrier();
    }
  }

  // ----- loss: yt from global (one-time), yp rows from LDS -----
  const float a = alpha;
  const int pbase = perm * NF;
  const float p0 = yp_sh[pbase + 0];
  const float p1 = yp_sh[pbase + 1];
  const float dx = x - p1;
  const float da = a - p0;
  float s2 = 0.0f;
#pragma unroll
  for (int f = 2; f < NF; ++f) {
    const float d = ytb[i * NF + f] - yp_sh[pbase + f];
    s2 += d * d;
  }
  float l = a * 5.0f * (dx * dx)
          + a * (da * da)
          + (1.0f - a) * 0.5f * (da * da)
          + a * s2;

#pragma unroll
  for (int off = 32; off > 0; off >>= 1) l += __shfl_down(l, off);
  if (i == 0) atomicAdd(out, l);
}

extern "C" void kernel_launch(void* const* d_in, const int* in_sizes, int n_in,
                              void* d_out, int out_size, void* d_ws, size_t ws_size,
                              hipStream_t stream) {
  const float* yt = (const float*)d_in[0];
  const float* yp = (const float*)d_in[1];
  float* out = (float*)d_out;
  const int B = in_sizes[0] / ROWF;

  hipMemsetAsync(out, 0, sizeof(float) * (size_t)out_size, stream);
  spotting_loss_kernel<<<B, 64, 0, stream>>>(yt, yp, out);
}

// Round 4
// 110.044 us; speedup vs baseline: 1.0042x; 1.0042x over previous
//
#include <hip/hip_runtime.h>
#include <stdint.h>

// SpottingLoss: B=2048, N=64, F=19. Two-phase greedy auction matching
// (bitwise-exact replica of the reference lax.scan; absmax 0.0 R1-R3)
// + permuted loss -> scalar.
//
// R4 insight: R1-R3 all measured ~50 us regardless of inner-loop structure;
// even fully-cached replays (FETCH~0) took 49 us. Invariant = the tail of
// 2048 same-address global atomicAdds (WRITE_SIZE was exactly 2048 x 32 B:
// each atomic was a serialized memory-side RMW, ~25 ns each ~= 51 us).
// Fix: per-block partial -> d_ws[blockIdx] (plain store), second 1-block
// kernel reduces 2048 floats and writes out[0] directly (memset dropped).

#define NN 64
#define NF 19
#define ROWF (NN * NF)   // 1216
#define ROW4 (ROWF / 4)  // 304

__device__ __forceinline__ unsigned umin2(unsigned a, unsigned b) {
  return a < b ? a : b;
}

__global__ __launch_bounds__(64, 2) void spotting_loss_kernel(
    const float* __restrict__ yt, const float* __restrict__ yp,
    float* __restrict__ partial)
{
  const int b = blockIdx.x;
  const int i = threadIdx.x;

  __shared__ float yp_sh[ROWF];
  __shared__ unsigned long long key_sh[NN];

  const float* __restrict__ ytb = yt + (size_t)b * ROWF;
  const float4* __restrict__ yp4 = (const float4*)(yp + (size_t)b * ROWF);
  float4* yp_sh4 = (float4*)yp_sh;
#pragma unroll
  for (int t = 0; t < 5; ++t) {
    const int idx = t * NN + i;
    if (idx < ROW4) yp_sh4[idx] = yp4[idx];
  }
  key_sh[i] = 0ull;               // tag 0 == never written
  const float alpha = ytb[i * NF + 0];
  const float x     = ytb[i * NF + 1];
  __syncthreads();

  // D1 row in registers (broadcast LDS reads).
  float D1v[NN];
#pragma unroll
  for (int j = 0; j < NN; ++j)
    D1v[j] = 1.0f - fabsf(x - yp_sh[j * NF + 1]);

  unsigned long long hbits = ~0ull;  // active columns
  int perm = 0, jmax = 0;
  unsigned long long mykey = 0;
  float best = 0.0f;
  unsigned tag = 0;

  for (int phase = 0; phase < 2; ++phase) {
    bool vlive  = (phase == 0) ? (alpha > 0.5f) : (alpha < 0.5f);
    bool rescan = vlive;

    for (int it = 0; it < NN; ++it) {
      if (__ballot(vlive) == 0ull) break;
      ++tag;

      if (rescan) {
        float m[NN];
#pragma unroll
        for (int j = 0; j < NN; ++j)
          m[j] = ((hbits >> j) & 1ull) ? D1v[j] : 0.0f;

        float t32[32], t16[16], t8[8], t4[4];
#pragma unroll
        for (int j = 0; j < 32; ++j) t32[j] = fmaxf(m[j], m[j + 32]);
#pragma unroll
        for (int j = 0; j < 16; ++j) t16[j] = fmaxf(t32[j], t32[j + 16]);
#pragma unroll
        for (int j = 0; j < 8; ++j)  t8[j]  = fmaxf(t16[j], t16[j + 8]);
#pragma unroll
        for (int j = 0; j < 4; ++j)  t4[j]  = fmaxf(t8[j], t8[j + 4]);
        best = fmaxf(fmaxf(t4[0], t4[1]), fmaxf(t4[2], t4[3]));

        unsigned c32[32], c16[16], c8[8], c4[4];
#pragma unroll
        for (int j = 0; j < 32; ++j) {
          const unsigned a0 = (m[j]      == best) ? (unsigned)j        : 255u;
          const unsigned a1 = (m[j + 32] == best) ? (unsigned)(j + 32) : 255u;
          c32[j] = umin2(a0, a1);
        }
#pragma unroll
        for (int j = 0; j < 16; ++j) c16[j] = umin2(c32[j], c32[j + 16]);
#pragma unroll
        for (int j = 0; j < 8; ++j)  c8[j]  = umin2(c16[j], c16[j + 8]);
#pragma unroll
        for (int j = 0; j < 4; ++j)  c4[j]  = umin2(c8[j], c8[j + 4]);
        jmax = (int)umin2(umin2(c4[0], c4[1]), umin2(c4[2], c4[3]));
        rescan = false;
      }

      if (vlive) {
        mykey = ((unsigned long long)tag << 38) |
                ((unsigned long long)__float_as_uint(best) << 6) |
                (unsigned long long)(63 - i);
        atomicMax(&key_sh[jmax], mykey);   // LDS atomic: cheap, conflict-few
      }
      __builtin_amdgcn_wave_barrier();     // DS pipe in-order within a wave

      const unsigned long long kc = key_sh[i];     // my column's key
      const unsigned long long kw = key_sh[jmax];  // my target's key
      const unsigned long long killed =
          __ballot((unsigned)(kc >> 38) == tag);   // fresh tag == matched col

      if (vlive) {
        if (kw == mykey) {        // best bidder -> matched
          perm = jmax;
          vlive = false;
        } else {
          rescan = true;          // column taken by a stronger bidder
        }
      }
      hbits &= ~killed;
      __builtin_amdgcn_wave_barrier();
    }
  }

  // ----- loss -----
  const float a = alpha;
  const int pbase = perm * NF;
  const float p0 = yp_sh[pbase + 0];
  const float p1 = yp_sh[pbase + 1];
  const float dx = x - p1;
  const float da = a - p0;
  float s2 = 0.0f;
#pragma unroll
  for (int f = 2; f < NF; ++f) {
    const float d = ytb[i * NF + f] - yp_sh[pbase + f];
    s2 += d * d;
  }
  float l = a * 5.0f * (dx * dx)
          + a * (da * da)
          + (1.0f - a) * 0.5f * (da * da)
          + a * s2;

#pragma unroll
  for (int off = 32; off > 0; off >>= 1) l += __shfl_down(l, off);
  if (i == 0) partial[b] = l;    // plain store -- no atomic contention
}

__global__ __launch_bounds__(1024) void reduce_kernel(
    const float* __restrict__ partial, float* __restrict__ out, int n)
{
  __shared__ float wsum[16];
  const int t = threadIdx.x;
  float s = 0.0f;
  for (int idx = t; idx < n; idx += 1024) s += partial[idx];
#pragma unroll
  for (int off = 32; off > 0; off >>= 1) s += __shfl_down(s, off);
  if ((t & 63) == 0) wsum[t >> 6] = s;
  __syncthreads();
  if (t < 64) {                  // wave 0 finishes: 16 partials -> 1
    float v = (t < 16) ? wsum[t] : 0.0f;
#pragma unroll
    for (int off = 32; off > 0; off >>= 1) v += __shfl_down(v, off);
    if (t == 0) out[0] = v;
  }
}

extern "C" void kernel_launch(void* const* d_in, const int* in_sizes, int n_in,
                              void* d_out, int out_size, void* d_ws, size_t ws_size,
                              hipStream_t stream) {
  const float* yt = (const float*)d_in[0];
  const float* yp = (const float*)d_in[1];
  float* out = (float*)d_out;
  float* partial = (float*)d_ws;
  const int B = in_sizes[0] / ROWF;

  spotting_loss_kernel<<<B, 64, 0, stream>>>(yt, yp, partial);
  reduce_kernel<<<1, 1024, 0, stream>>>(partial, out, B);
}